// Round 1
// baseline (360.839 us; speedup 1.0000x reference)
//
#include <hip/hip_runtime.h>
#include <math.h>

#define N_ROWS 32768
#define N_COLS 2048
constexpr float S_CONST = 1.05f;

__device__ __forceinline__ float wave_reduce_sum(float v) {
    #pragma unroll
    for (int off = 32; off > 0; off >>= 1) v += __shfl_down(v, off, 64);
    return v;
}
__device__ __forceinline__ float wave_reduce_max(float v) {
    #pragma unroll
    for (int off = 32; off > 0; off >>= 1) v = fmaxf(v, __shfl_down(v, off, 64));
    return v;
}

// One block (256 threads) per row. Single pass over the 256 MB matrix:
// computes row sum / sumsq (incl. target col), max & sum-exp EXCLUDING the
// target col, grabs the target logit, and atomically accumulates per-class
// sums for the group-std computation.
__global__ __launch_bounds__(256) void k_rowpass(
    const float* __restrict__ X, const long long* __restrict__ lbl,
    float* __restrict__ g_sum, float* __restrict__ g_sq, float* __restrict__ g_cnt,
    float* __restrict__ row_max, float* __restrict__ row_se, float* __restrict__ row_lc)
{
    const int row  = blockIdx.x;
    const int t    = threadIdx.x;
    const int wave = t >> 6;
    const int lane = t & 63;
    const int col  = (int)lbl[row];

    const float4* xr = (const float4*)(X + (size_t)row * N_COLS);
    float4 v0 = xr[t];        // cols [4t, 4t+4)
    float4 v1 = xr[t + 256];  // cols [4(t+256), ...)
    float vals[8] = {v0.x, v0.y, v0.z, v0.w, v1.x, v1.y, v1.z, v1.w};

    __shared__ float s_lc;
    __shared__ float sh[12];
    __shared__ float s_bmax, s_bsum, s_bsq;

    float sum = 0.f, sq = 0.f;
    #pragma unroll
    for (int i = 0; i < 8; i++) {
        int j = (i < 4) ? (t * 4 + i) : ((t + 256) * 4 + (i - 4));
        float x = vals[i];
        sum += x;
        sq = fmaf(x, x, sq);
        if (j == col) { s_lc = x; vals[i] = -INFINITY; }  // exclude target from max/sumexp
    }
    float mx = -INFINITY;
    #pragma unroll
    for (int i = 0; i < 8; i++) mx = fmaxf(mx, vals[i]);

    float wsum = wave_reduce_sum(sum);
    float wsq  = wave_reduce_sum(sq);
    float wmx  = wave_reduce_max(mx);
    if (lane == 0) { sh[wave] = wsum; sh[4 + wave] = wsq; sh[8 + wave] = wmx; }
    __syncthreads();
    if (t == 0) {
        s_bsum = sh[0] + sh[1] + sh[2] + sh[3];
        s_bsq  = sh[4] + sh[5] + sh[6] + sh[7];
        s_bmax = fmaxf(fmaxf(sh[8], sh[9]), fmaxf(sh[10], sh[11]));
    }
    __syncthreads();

    const float bmax = s_bmax;
    float se = 0.f;
    #pragma unroll
    for (int i = 0; i < 8; i++) se += expf(vals[i] - bmax);  // exp(-inf)=0 drops target col

    float wse = wave_reduce_sum(se);
    if (lane == 0) sh[wave] = wse;
    __syncthreads();
    if (t == 0) {
        float bse = sh[0] + sh[1] + sh[2] + sh[3];
        row_max[row] = bmax;
        row_se[row]  = bse;
        row_lc[row]  = s_lc;
        atomicAdd(&g_sum[col], s_bsum);
        atomicAdd(&g_sq[col],  s_bsq);
        atomicAdd(&g_cnt[col], 1.0f);
    }
}

// Per-class margin m[c] = 0.5*sqrt(max(E[x^2]-E[x]^2, 0)) over the group's
// [n_c, C] block (biased, cnt = rows*C, clamped to >=1 like the reference).
__global__ __launch_bounds__(256) void k_classm(
    const float* __restrict__ g_sum, const float* __restrict__ g_sq,
    const float* __restrict__ g_cnt, float* __restrict__ m)
{
    int c = blockIdx.x * 256 + threadIdx.x;
    if (c >= N_COLS) return;
    float cnt  = fmaxf(g_cnt[c] * (float)N_COLS, 1.0f);
    float mean = g_sum[c] / cnt;
    float var  = fmaxf(g_sq[c] / cnt - mean * mean, 0.0f);
    m[c] = 0.5f * sqrtf(var);
}

// Per-row epilogue: margin-adjusted target logit -> logsumexp fixup -> nll;
// mean over N accumulated into out[0].
__global__ __launch_bounds__(256) void k_nll(
    const long long* __restrict__ lbl, const float* __restrict__ m,
    const float* __restrict__ row_max, const float* __restrict__ row_se,
    const float* __restrict__ row_lc, float* __restrict__ out)
{
    float acc = 0.f;
    for (int n = blockIdx.x * blockDim.x + threadIdx.x; n < N_ROWS;
         n += gridDim.x * blockDim.x) {
        int   c   = (int)lbl[n];
        float x   = row_lc[n];
        float mm  = m[c];
        float xm  = x - mm;
        float val = (x > 0.f) ? (xm / S_CONST) : (xm * S_CONST);
        float rmx = row_max[n];
        float M   = fmaxf(rmx, val);
        float lse = logf(row_se[n] * expf(rmx - M) + expf(val - M)) + M;
        acc += (lse - val);
    }
    __shared__ float sh[4];
    float w = wave_reduce_sum(acc);
    int wave = threadIdx.x >> 6, lane = threadIdx.x & 63;
    if (lane == 0) sh[wave] = w;
    __syncthreads();
    if (threadIdx.x == 0) {
        float b = sh[0] + sh[1] + sh[2] + sh[3];
        atomicAdd(out, b * (1.0f / (float)N_ROWS));
    }
}

extern "C" void kernel_launch(void* const* d_in, const int* in_sizes, int n_in,
                              void* d_out, int out_size, void* d_ws, size_t ws_size,
                              hipStream_t stream) {
    const float*     X   = (const float*)d_in[0];
    const long long* lbl = (const long long*)d_in[1];
    float*           out = (float*)d_out;
    float*           ws  = (float*)d_ws;

    const int C = N_COLS, N = N_ROWS;
    float* g_sum   = ws;
    float* g_sq    = ws + C;
    float* g_cnt   = ws + 2 * C;
    float* m       = ws + 3 * C;
    float* row_max = ws + 4 * C;
    float* row_se  = row_max + N;
    float* row_lc  = row_se + N;

    // Zero class accumulators and the scalar output (graph-capture safe).
    hipMemsetAsync(ws, 0, 3 * C * sizeof(float), stream);
    hipMemsetAsync(d_out, 0, sizeof(float), stream);

    k_rowpass<<<N, 256, 0, stream>>>(X, lbl, g_sum, g_sq, g_cnt, row_max, row_se, row_lc);
    k_classm<<<(C + 255) / 256, 256, 0, stream>>>(g_sum, g_sq, g_cnt, m);
    k_nll<<<64, 256, 0, stream>>>(lbl, m, row_max, row_se, row_lc, out);
}

// Round 2
// 359.552 us; speedup vs baseline: 1.0036x; 1.0036x over previous
//
#include <hip/hip_runtime.h>
#include <math.h>

#define N_ROWS 32768
#define N_COLS 2048
constexpr float S_CONST = 1.05f;

// Butterfly reductions: result valid in ALL 64 lanes (no broadcast needed).
__device__ __forceinline__ float wred_sum(float v) {
    #pragma unroll
    for (int off = 32; off > 0; off >>= 1) v += __shfl_xor(v, off, 64);
    return v;
}
__device__ __forceinline__ float wred_max(float v) {
    #pragma unroll
    for (int off = 32; off > 0; off >>= 1) v = fmaxf(v, __shfl_xor(v, off, 64));
    return v;
}

// Single dispatch replacing two hipMemsetAsync: zero class accumulators + out.
__global__ __launch_bounds__(256) void k_init(float* __restrict__ ws,
                                              float* __restrict__ out) {
    int i = blockIdx.x * 256 + threadIdx.x;
    if (i < 3 * N_COLS) ws[i] = 0.f;
    if (i == 0) out[0] = 0.f;
}

// ONE WAVE PER ROW (4 rows / 256-thread block). Each lane: 8 float4 loads
// (32 cols), issued back-to-back for MLP. All reductions are in-register
// shfl butterflies — no LDS, no __syncthreads. Single pass over 256 MB:
// row sum/sumsq (incl. target), max & sum-exp EXCLUDING target, target
// logit, plus 3 atomics/row for the per-class stats.
__global__ __launch_bounds__(256) void k_rowpass(
    const float* __restrict__ X, const long long* __restrict__ lbl,
    float* __restrict__ g_sum, float* __restrict__ g_sq, float* __restrict__ g_cnt,
    float* __restrict__ row_max, float* __restrict__ row_se, float* __restrict__ row_lc)
{
    const int lane = threadIdx.x & 63;
    const int row  = blockIdx.x * 4 + (threadIdx.x >> 6);
    const int col  = (int)lbl[row];

    const float4* xr = (const float4*)(X + (size_t)row * N_COLS);
    float4 v[8];
    #pragma unroll
    for (int k = 0; k < 8; k++) v[k] = xr[lane + 64 * k];  // 8 outstanding dwordx4

    float sum = 0.f, sq = 0.f, mx = -INFINITY, lc = 0.f;
    #pragma unroll
    for (int k = 0; k < 8; k++) {
        const int base = 4 * (lane + 64 * k);
        float e0 = v[k].x, e1 = v[k].y, e2 = v[k].z, e3 = v[k].w;
        sum += e0 + e1 + e2 + e3;
        sq = fmaf(e0, e0, sq); sq = fmaf(e1, e1, sq);
        sq = fmaf(e2, e2, sq); sq = fmaf(e3, e3, sq);
        // exclude target col from max/sum-exp, capture its logit
        if (base + 0 == col) { lc = e0; e0 = -INFINITY; }
        if (base + 1 == col) { lc = e1; e1 = -INFINITY; }
        if (base + 2 == col) { lc = e2; e2 = -INFINITY; }
        if (base + 3 == col) { lc = e3; e3 = -INFINITY; }
        mx = fmaxf(fmaxf(mx, fmaxf(e0, e1)), fmaxf(e2, e3));
        v[k].x = e0; v[k].y = e1; v[k].z = e2; v[k].w = e3;
    }
    sum = wred_sum(sum);
    sq  = wred_sum(sq);
    mx  = wred_max(mx);
    lc  = __shfl(lc, (col >> 2) & 63, 64);  // owning lane -> all lanes

    float se = 0.f;
    #pragma unroll
    for (int k = 0; k < 8; k++) {
        se += __expf(v[k].x - mx);  // exp(-inf)=0 drops the target col
        se += __expf(v[k].y - mx);
        se += __expf(v[k].z - mx);
        se += __expf(v[k].w - mx);
    }
    se = wred_sum(se);

    if (lane == 0) {
        row_max[row] = mx;
        row_se[row]  = se;
        row_lc[row]  = lc;
        atomicAdd(&g_sum[col], sum);
        atomicAdd(&g_sq[col],  sq);
        atomicAdd(&g_cnt[col], 1.0f);
    }
}

// Per-row epilogue. m[c] computed inline from class sums (redundant per row
// but ~5 VALU ops against L2-resident 24 KB arrays — cheaper than a separate
// dispatch). nll = lse - val; mean accumulated into out[0].
__global__ __launch_bounds__(256) void k_nll(
    const long long* __restrict__ lbl,
    const float* __restrict__ g_sum, const float* __restrict__ g_sq,
    const float* __restrict__ g_cnt,
    const float* __restrict__ row_max, const float* __restrict__ row_se,
    const float* __restrict__ row_lc, float* __restrict__ out)
{
    float acc = 0.f;
    for (int n = blockIdx.x * blockDim.x + threadIdx.x; n < N_ROWS;
         n += gridDim.x * blockDim.x) {
        int   c    = (int)lbl[n];
        float cnt  = fmaxf(g_cnt[c] * (float)N_COLS, 1.0f);
        float mean = g_sum[c] / cnt;
        float var  = fmaxf(g_sq[c] / cnt - mean * mean, 0.0f);
        float mm   = 0.5f * sqrtf(var);
        float x    = row_lc[n];
        float xm   = x - mm;
        float val  = (x > 0.f) ? (xm / S_CONST) : (xm * S_CONST);
        float rmx  = row_max[n];
        float M    = fmaxf(rmx, val);
        float lse  = logf(row_se[n] * expf(rmx - M) + expf(val - M)) + M;
        acc += (lse - val);
    }
    __shared__ float sh[4];
    float w = wred_sum(acc);
    int wave = threadIdx.x >> 6, lane = threadIdx.x & 63;
    if (lane == 0) sh[wave] = w;
    __syncthreads();
    if (threadIdx.x == 0) {
        float b = sh[0] + sh[1] + sh[2] + sh[3];
        atomicAdd(out, b * (1.0f / (float)N_ROWS));
    }
}

extern "C" void kernel_launch(void* const* d_in, const int* in_sizes, int n_in,
                              void* d_out, int out_size, void* d_ws, size_t ws_size,
                              hipStream_t stream) {
    const float*     X   = (const float*)d_in[0];
    const long long* lbl = (const long long*)d_in[1];
    float*           out = (float*)d_out;
    float*           ws  = (float*)d_ws;

    const int C = N_COLS, N = N_ROWS;
    float* g_sum   = ws;
    float* g_sq    = ws + C;
    float* g_cnt   = ws + 2 * C;
    float* row_max = ws + 3 * C;
    float* row_se  = row_max + N;
    float* row_lc  = row_se + N;

    k_init<<<(3 * C + 255) / 256, 256, 0, stream>>>(ws, out);
    k_rowpass<<<N / 4, 256, 0, stream>>>(X, lbl, g_sum, g_sq, g_cnt,
                                         row_max, row_se, row_lc);
    k_nll<<<64, 256, 0, stream>>>(lbl, g_sum, g_sq, g_cnt,
                                  row_max, row_se, row_lc, out);
}